// Round 4
// baseline (561.343 us; speedup 1.0000x reference)
//
#include <hip/hip_runtime.h>
#include <stdint.h>

#define N_VOX 262144
#define CCH 64
#define KOFF 27

typedef short v8s __attribute__((ext_vector_type(8)));
typedef float v4f __attribute__((ext_vector_type(4)));

__device__ __forceinline__ unsigned short f2bf(float f) {
  unsigned u = __float_as_uint(f);
  u += 0x7fff + ((u >> 16) & 1);   // RNE
  return (unsigned short)(u >> 16);
}

// --- deterministic sniff of the mask buffer's dtype (byte-bool vs 32-bit) ---
__global__ void prep_flag_k(const unsigned* __restrict__ m, int* __restrict__ flag) {
  if (threadIdx.x == 0) {
    int wordlike = 1;  // int32 0/1 or float32 0.0/1.0
    for (int i = 0; i < 256; ++i) {
      unsigned v = m[i];
      if (v > 1u && v != 0x3f800000u) { wordlike = 0; break; }
    }
    *flag = wordlike ? 0 : 2;   // 0: read as u32 words, 2: read as bytes
  }
}

__global__ void prep_mask_k(const void* __restrict__ m, const int* __restrict__ flag,
                            unsigned char* __restrict__ mb, int n) {
  int f = *flag;
  for (int i = blockIdx.x * blockDim.x + threadIdx.x; i < n; i += gridDim.x * blockDim.x) {
    unsigned char v;
    if (f == 2) v = (((const unsigned char*)m)[i] != 0);
    else        v = (((const unsigned*)m)[i] != 0u);
    mb[i] = v;
  }
}

// --- features fp32 -> bf16 table (halves gather traffic, frags load direct) ---
__global__ void prep_feat_k(const float* __restrict__ src, unsigned short* __restrict__ dst, int n8) {
  int i = blockIdx.x * blockDim.x + threadIdx.x;
  if (i >= n8) return;
  const float4* s4 = (const float4*)src;
  float4 a = s4[i * 2], b = s4[i * 2 + 1];
  v8s v;
  v[0] = (short)f2bf(a.x); v[1] = (short)f2bf(a.y);
  v[2] = (short)f2bf(a.z); v[3] = (short)f2bf(a.w);
  v[4] = (short)f2bf(b.x); v[5] = (short)f2bf(b.y);
  v[6] = (short)f2bf(b.z); v[7] = (short)f2bf(b.w);
  ((v8s*)dst)[i] = v;
}

// --- W [27][cin][cout] fp32 -> Wt bf16 [27][cout][cin] (plain transpose) ---
__global__ void prep_w_k(const float* __restrict__ w, unsigned short* __restrict__ wt) {
  int i = blockIdx.x * blockDim.x + threadIdx.x;
  if (i >= KOFF * CCH * CCH) return;
  int k = i >> 12, rem = i & 4095, kk = rem >> 6, col = rem & 63;
  wt[(k << 12) + (col << 6) + kk] = f2bf(w[i]);
}

// One pipeline stage. Uses A(k) [gathered 2 stages ago, in-place] and W(k)
// [prefetched 1 stage ago]. Then, after last use of each register set:
// prefetch W(k+1) into bu, gather A(k+2) into a* (idx/mask preloaded 2 stages
// ago into j/n), and load idx/mask(k+4) into j/n. No copies, no barriers.
__device__ __forceinline__ void conv_body(
    int k, bool last,
    const v8s* __restrict__ src, const int* __restrict__ nbr,
    const unsigned char* __restrict__ mb, const v8s* __restrict__ wptr,
    int r0, int r1, int g, int l15,
    v8s& a0, v8s& a1, v8s& a2, v8s& a3,
    v8s (&bu)[8], int& j0, int& j1, bool& n0, bool& n1,
    v4f (&acc0)[4], v4f (&acc1)[4])
{
#pragma unroll
  for (int ct = 0; ct < 4; ++ct) {
    acc0[ct] = __builtin_amdgcn_mfma_f32_16x16x32_bf16(a0, bu[ct],     acc0[ct], 0, 0, 0);
    acc0[ct] = __builtin_amdgcn_mfma_f32_16x16x32_bf16(a1, bu[4 + ct], acc0[ct], 0, 0, 0);
    acc1[ct] = __builtin_amdgcn_mfma_f32_16x16x32_bf16(a2, bu[ct],     acc1[ct], 0, 0, 0);
    acc1[ct] = __builtin_amdgcn_mfma_f32_16x16x32_bf16(a3, bu[4 + ct], acc1[ct], 0, 0, 0);
  }
  if (last) return;

  // W(k+1) fragment prefetch (overwrite-after-use, contiguous 64B lines)
  const int wk = (k + 1) << 9;
#pragma unroll
  for (int ct = 0; ct < 4; ++ct) {
    const int wb = ((ct * 16 + l15) << 3) + g;
    bu[ct]     = wptr[wk + wb];
    bu[4 + ct] = wptr[wk + wb + 4];
  }

  // gathers for k+2 (j/n hold idx/mask(k+2), loaded 2 stages ago)
  if (k + 2 < KOFF) {
    a0 = {}; a1 = {}; a2 = {}; a3 = {};
    if (n0) { a0 = src[j0 * 8 + g]; a1 = src[j0 * 8 + 4 + g]; }
    if (n1) { a2 = src[j1 * 8 + g]; a3 = src[j1 * 8 + 4 + g]; }
  }

  // idx/mask for k+4 (into the slots just consumed)
  const int kj = (k + 4 < KOFF) ? k + 4 : KOFF - 1;
  j0 = nbr[kj * N_VOX + r0]; j1 = nbr[kj * N_VOX + r1];
  n0 = mb[kj * N_VOX + r0];  n1 = mb[kj * N_VOX + r1];
}

// --- one sparse-conv layer: barrier-free, copy-free 2-stage pipeline ---
// 128 rows/block (4 waves x 32 rows). LAYER==1: bf16 h. LAYER==2: f32+resid.
template <int LAYER>
__global__ __launch_bounds__(256, 4)
void conv_layer_k(const v8s* __restrict__ src, const int* __restrict__ nbr,
                  const unsigned char* __restrict__ mb,
                  const v8s* __restrict__ wptr, const float* __restrict__ bias,
                  const float* __restrict__ resid, void* __restrict__ outp) {
  const int tid = threadIdx.x;
  const int lane = tid & 63;
  const int wv = tid >> 6;
  const int l15 = lane & 15;
  const int g = lane >> 4;
  const int rowbase = blockIdx.x * 128 + wv * 32;
  const int r0 = rowbase + l15;
  const int r1 = rowbase + 16 + l15;

  // ---- prologue: A(0)->aE, A(1)->aO, idx/mask(2)->E, (3)->O, W(0)->bu ----
  int jE0 = nbr[r0], jE1 = nbr[r1];
  int jO0 = nbr[N_VOX + r0], jO1 = nbr[N_VOX + r1];
  bool nE0 = mb[r0], nE1 = mb[r1];
  bool nO0 = mb[N_VOX + r0], nO1 = mb[N_VOX + r1];

  v8s aE0 = {}, aE1 = {}, aE2 = {}, aE3 = {};
  v8s aO0 = {}, aO1 = {}, aO2 = {}, aO3 = {};
  if (nE0) { aE0 = src[jE0 * 8 + g]; aE1 = src[jE0 * 8 + 4 + g]; }
  if (nE1) { aE2 = src[jE1 * 8 + g]; aE3 = src[jE1 * 8 + 4 + g]; }
  if (nO0) { aO0 = src[jO0 * 8 + g]; aO1 = src[jO0 * 8 + 4 + g]; }
  if (nO1) { aO2 = src[jO1 * 8 + g]; aO3 = src[jO1 * 8 + 4 + g]; }

  jE0 = nbr[2 * N_VOX + r0]; jE1 = nbr[2 * N_VOX + r1];
  nE0 = mb[2 * N_VOX + r0];  nE1 = mb[2 * N_VOX + r1];
  jO0 = nbr[3 * N_VOX + r0]; jO1 = nbr[3 * N_VOX + r1];
  nO0 = mb[3 * N_VOX + r0];  nO1 = mb[3 * N_VOX + r1];

  v8s bu[8];
#pragma unroll
  for (int ct = 0; ct < 4; ++ct) {
    const int wb = ((ct * 16 + l15) << 3) + g;
    bu[ct]     = wptr[wb];
    bu[4 + ct] = wptr[wb + 4];
  }

  v4f acc0[4] = {}, acc1[4] = {};

  for (int k = 0; k < KOFF - 1; k += 2) {
    conv_body(k,     false, src, nbr, mb, wptr, r0, r1, g, l15,
              aE0, aE1, aE2, aE3, bu, jE0, jE1, nE0, nE1, acc0, acc1);
    conv_body(k + 1, false, src, nbr, mb, wptr, r0, r1, g, l15,
              aO0, aO1, aO2, aO3, bu, jO0, jO1, nO0, nO1, acc0, acc1);
  }
  conv_body(KOFF - 1, true, src, nbr, mb, wptr, r0, r1, g, l15,
            aE0, aE1, aE2, aE3, bu, jE0, jE1, nE0, nE1, acc0, acc1);

  float bv[4];
#pragma unroll
  for (int ct = 0; ct < 4; ++ct) bv[ct] = bias[ct * 16 + l15];

#pragma unroll
  for (int rt = 0; rt < 2; ++rt) {
    int row0 = rowbase + rt * 16 + g * 4;   // D row = (lane>>4)*4 + i
#pragma unroll
    for (int ct = 0; ct < 4; ++ct) {
      int col = ct * 16 + l15;              // D col = lane & 15
      const v4f& a = rt ? acc1[ct] : acc0[ct];
#pragma unroll
      for (int i = 0; i < 4; ++i) {
        float v = a[i] + bv[ct];
        int o = (row0 + i) * CCH + col;
        if (LAYER == 1) ((unsigned short*)outp)[o] = f2bf(v);
        else            ((float*)outp)[o] = v + resid[o];
      }
    }
  }
}

extern "C" void kernel_launch(void* const* d_in, const int* in_sizes, int n_in,
                              void* d_out, int out_size, void* d_ws, size_t ws_size,
                              hipStream_t stream) {
  const float* feat = (const float*)d_in[0];
  const int* nbr    = (const int*)d_in[1];
  const void* mask  = d_in[2];
  const float* w1   = (const float*)d_in[3];
  const float* b1   = (const float*)d_in[4];
  const float* w2   = (const float*)d_in[5];
  const float* b2   = (const float*)d_in[6];

  char* ws = (char*)d_ws;
  unsigned short* featb = (unsigned short*)ws;                    // 33,554,432 B
  unsigned short* hb    = (unsigned short*)(ws + 33554432);       // 33,554,432 B
  unsigned char*  maskb = (unsigned char*)(ws + 67108864);        //  7,077,888 B
  unsigned short* wt1   = (unsigned short*)(ws + 74186752);       //    221,184 B
  unsigned short* wt2   = (unsigned short*)(ws + 74407936);       //    221,184 B
  int*            flag  = (int*)(ws + 74629120);

  prep_flag_k<<<1, 64, 0, stream>>>((const unsigned*)mask, flag);
  prep_mask_k<<<4096, 256, 0, stream>>>(mask, flag, maskb, KOFF * N_VOX);
  prep_feat_k<<<8192, 256, 0, stream>>>(feat, featb, N_VOX * CCH / 8);
  prep_w_k<<<432, 256, 0, stream>>>(w1, wt1);
  prep_w_k<<<432, 256, 0, stream>>>(w2, wt2);

  conv_layer_k<1><<<2048, 256, 0, stream>>>((const v8s*)featb, nbr, maskb,
                                            (const v8s*)wt1, b1, nullptr, (void*)hb);
  conv_layer_k<2><<<2048, 256, 0, stream>>>((const v8s*)hb, nbr, maskb,
                                            (const v8s*)wt2, b2, feat, (void*)d_out);
}

// Round 5
// 288.510 us; speedup vs baseline: 1.9457x; 1.9457x over previous
//
#include <hip/hip_runtime.h>
#include <stdint.h>

#define N_VOX 262144
#define CCH 64
#define KOFF 27

typedef short v8s __attribute__((ext_vector_type(8)));
typedef float v4f __attribute__((ext_vector_type(4)));

// global -> LDS direct DMA, 16B/lane; LDS dest = wave-uniform base + lane*16
#define GL_LDS16(gp, lp) __builtin_amdgcn_global_load_lds(                  \
    (const __attribute__((address_space(1))) void*)(gp),                    \
    (__attribute__((address_space(3))) void*)(lp), 16, 0, 0)

__device__ __forceinline__ unsigned short f2bf(float f) {
  unsigned u = __float_as_uint(f);
  u += 0x7fff + ((u >> 16) & 1);   // RNE
  return (unsigned short)(u >> 16);
}

// --- deterministic sniff of the mask buffer's dtype (byte-bool vs 32-bit) ---
__global__ void prep_flag_k(const unsigned* __restrict__ m, int* __restrict__ flag) {
  if (threadIdx.x == 0) {
    int wordlike = 1;  // int32 0/1 or float32 0.0/1.0
    for (int i = 0; i < 256; ++i) {
      unsigned v = m[i];
      if (v > 1u && v != 0x3f800000u) { wordlike = 0; break; }
    }
    *flag = wordlike ? 0 : 2;   // 0: read as u32 words, 2: read as bytes
  }
}

__global__ void prep_mask_k(const void* __restrict__ m, const int* __restrict__ flag,
                            unsigned char* __restrict__ mb, int n) {
  int f = *flag;
  for (int i = blockIdx.x * blockDim.x + threadIdx.x; i < n; i += gridDim.x * blockDim.x) {
    unsigned char v;
    if (f == 2) v = (((const unsigned char*)m)[i] != 0);
    else        v = (((const unsigned*)m)[i] != 0u);
    mb[i] = v;
  }
}

// --- features fp32 -> bf16 table (halves gather traffic, frags load direct) ---
__global__ void prep_feat_k(const float* __restrict__ src, unsigned short* __restrict__ dst, int n8) {
  int i = blockIdx.x * blockDim.x + threadIdx.x;
  if (i >= n8) return;
  const float4* s4 = (const float4*)src;
  float4 a = s4[i * 2], b = s4[i * 2 + 1];
  v8s v;
  v[0] = (short)f2bf(a.x); v[1] = (short)f2bf(a.y);
  v[2] = (short)f2bf(a.z); v[3] = (short)f2bf(a.w);
  v[4] = (short)f2bf(b.x); v[5] = (short)f2bf(b.y);
  v[6] = (short)f2bf(b.z); v[7] = (short)f2bf(b.w);
  ((v8s*)dst)[i] = v;
}

// --- W [27][cin][cout] fp32 -> frag-order bf16: wf[k][ct*2+half][lane][8]
// so each wave's B-fragment load is one fully-coalesced dwordx4 per lane. ---
__global__ void prep_w_k(const float* __restrict__ w, unsigned short* __restrict__ wt) {
  int i = blockIdx.x * blockDim.x + threadIdx.x;
  if (i >= KOFF * CCH * CCH) return;          // 110592
  int e = i & 7, lane = (i >> 3) & 63, ch = (i >> 9) & 7, k = i >> 12;
  int ct = ch >> 1, half = ch & 1;
  int col = ct * 16 + (lane & 15);
  int kk = half * 32 + ((lane >> 4) << 3) + e;
  wt[i] = f2bf(w[(k << 12) + (kk << 6) + col]);
}

// One k-step. A(k) read from private LDS slot S (arrived: vmcnt(12) FIFO
// guarantee), masked, MFMA'd; then W(k+1)->bu, then gathers A(k+2) into S
// (issued last so bu's reg-dep wait never drains them), then idx/mask(k+4).
__device__ __forceinline__ void conv_body(
    int k, char* S,
    const v8s* __restrict__ src, const int* __restrict__ nbr,
    const unsigned char* __restrict__ mb, const v8s* __restrict__ wf,
    int lane, int g, int r0, int r1,
    int& j0, int& j1, unsigned char& g0, unsigned char& g1,
    unsigned char& m0, unsigned char& m1,
    v8s (&bu)[8], v4f (&acc0)[4], v4f (&acc1)[4])
{
  asm volatile("s_waitcnt vmcnt(12)" ::: "memory");   // A(k)'s 4 DMAs landed
  v8s a0 = *(const v8s*)(S + lane * 16);
  v8s a1 = *(const v8s*)(S + 1024 + lane * 16);
  v8s a2 = *(const v8s*)(S + 2048 + lane * 16);
  v8s a3 = *(const v8s*)(S + 3072 + lane * 16);
  asm volatile("s_waitcnt lgkmcnt(0)" ::: "memory");  // reads done before overwrite
  if (!m0) { a0 = (v8s){}; a1 = (v8s){}; }            // stale cells of skipped rows
  if (!m1) { a2 = (v8s){}; a3 = (v8s){}; }
  m0 = g0; m1 = g1;                                   // mask(k+2) for frag-use later

#pragma unroll
  for (int ct = 0; ct < 4; ++ct) {
    acc0[ct] = __builtin_amdgcn_mfma_f32_16x16x32_bf16(a0, bu[ct],     acc0[ct], 0, 0, 0);
    acc0[ct] = __builtin_amdgcn_mfma_f32_16x16x32_bf16(a1, bu[4 + ct], acc0[ct], 0, 0, 0);
    acc1[ct] = __builtin_amdgcn_mfma_f32_16x16x32_bf16(a2, bu[ct],     acc1[ct], 0, 0, 0);
    acc1[ct] = __builtin_amdgcn_mfma_f32_16x16x32_bf16(a3, bu[4 + ct], acc1[ct], 0, 0, 0);
  }

  if (k + 1 < KOFF) {     // W(k+1) -> bu (coalesced frag-order)
#pragma unroll
    for (int ct = 0; ct < 4; ++ct) {
      bu[ct]     = wf[((k + 1) * 8 + ct * 2) * 64 + lane];
      bu[4 + ct] = wf[((k + 1) * 8 + ct * 2 + 1) * 64 + lane];
    }
  }

  if (k + 2 < KOFF) {
    // gathers A(k+2) into this slot (just freed); exec-masked by g0/g1
    if (g0) {
      GL_LDS16(src + (size_t)j0 * 8 + g,     S);
      GL_LDS16(src + (size_t)j0 * 8 + 4 + g, S + 1024);
    }
    if (g1) {
      GL_LDS16(src + (size_t)j1 * 8 + g,     S + 2048);
      GL_LDS16(src + (size_t)j1 * 8 + 4 + g, S + 3072);
    }
    int kj = (k + 4 < KOFF) ? k + 4 : KOFF - 1;
    j0 = nbr[kj * N_VOX + r0]; j1 = nbr[kj * N_VOX + r1];
    g0 = mb[kj * N_VOX + r0];  g1 = mb[kj * N_VOX + r1];
  }
}

// --- one sparse-conv layer: barrier-free LDS-ring gather pipeline ---
// 4 waves x 32 rows; per-wave 2x4KB private ring slots. LAYER1: bf16 h,
// LAYER2: f32 + bias + residual.
template <int LAYER>
__global__ __launch_bounds__(256, 4)
void conv_layer_k(const v8s* __restrict__ src, const int* __restrict__ nbr,
                  const unsigned char* __restrict__ mb,
                  const v8s* __restrict__ wf, const float* __restrict__ bias,
                  const float* __restrict__ resid, void* __restrict__ outp) {
  __shared__ char ldsA[4 * 8192];
  const int tid = threadIdx.x;
  const int lane = tid & 63;
  const int wv = tid >> 6;
  const int l15 = lane & 15;
  const int g = lane >> 4;
  const int rowbase = blockIdx.x * 128 + wv * 32;
  const int r0 = rowbase + l15;
  const int r1 = rowbase + 16 + l15;
  char* slotE = ldsA + wv * 8192;
  char* slotO = slotE + 4096;

  // ---- prologue: gathers A(0)->E, A(1)->O; idx/mask(2)->E, (3)->O; W(0) ----
  int t0 = nbr[r0], t1 = nbr[r1];
  unsigned char p0 = mb[r0], p1 = mb[r1];
  int s0 = nbr[N_VOX + r0], s1 = nbr[N_VOX + r1];
  unsigned char q0 = mb[N_VOX + r0], q1 = mb[N_VOX + r1];

  if (p0) { GL_LDS16(src + (size_t)t0 * 8 + g, slotE);
            GL_LDS16(src + (size_t)t0 * 8 + 4 + g, slotE + 1024); }
  if (p1) { GL_LDS16(src + (size_t)t1 * 8 + g, slotE + 2048);
            GL_LDS16(src + (size_t)t1 * 8 + 4 + g, slotE + 3072); }
  if (q0) { GL_LDS16(src + (size_t)s0 * 8 + g, slotO);
            GL_LDS16(src + (size_t)s0 * 8 + 4 + g, slotO + 1024); }
  if (q1) { GL_LDS16(src + (size_t)s1 * 8 + g, slotO + 2048);
            GL_LDS16(src + (size_t)s1 * 8 + 4 + g, slotO + 3072); }

  int jE0 = nbr[2 * N_VOX + r0], jE1 = nbr[2 * N_VOX + r1];
  unsigned char gE0 = mb[2 * N_VOX + r0], gE1 = mb[2 * N_VOX + r1];
  int jO0 = nbr[3 * N_VOX + r0], jO1 = nbr[3 * N_VOX + r1];
  unsigned char gO0 = mb[3 * N_VOX + r0], gO1 = mb[3 * N_VOX + r1];
  unsigned char mE0 = p0, mE1 = p1, mO0 = q0, mO1 = q1;

  v8s bu[8];
#pragma unroll
  for (int ct = 0; ct < 4; ++ct) {
    bu[ct]     = wf[(ct * 2) * 64 + lane];
    bu[4 + ct] = wf[(ct * 2 + 1) * 64 + lane];
  }

  v4f acc0[4] = {}, acc1[4] = {};

#pragma unroll 1
  for (int k = 0; k < KOFF - 1; k += 2) {
    conv_body(k,     slotE, src, nbr, mb, wf, lane, g, r0, r1,
              jE0, jE1, gE0, gE1, mE0, mE1, bu, acc0, acc1);
    conv_body(k + 1, slotO, src, nbr, mb, wf, lane, g, r0, r1,
              jO0, jO1, gO0, gO1, mO0, mO1, bu, acc0, acc1);
  }
  conv_body(KOFF - 1, slotE, src, nbr, mb, wf, lane, g, r0, r1,
            jE0, jE1, gE0, gE1, mE0, mE1, bu, acc0, acc1);

  float bv[4];
#pragma unroll
  for (int ct = 0; ct < 4; ++ct) bv[ct] = bias[ct * 16 + l15];

#pragma unroll
  for (int rt = 0; rt < 2; ++rt) {
    int row0 = rowbase + rt * 16 + g * 4;   // D row = (lane>>4)*4 + i
#pragma unroll
    for (int ct = 0; ct < 4; ++ct) {
      int col = ct * 16 + l15;              // D col = lane & 15
      const v4f& a = rt ? acc1[ct] : acc0[ct];
#pragma unroll
      for (int i = 0; i < 4; ++i) {
        float v = a[i] + bv[ct];
        int o = (row0 + i) * CCH + col;
        if (LAYER == 1) ((unsigned short*)outp)[o] = f2bf(v);
        else            ((float*)outp)[o] = v + resid[o];
      }
    }
  }
}

extern "C" void kernel_launch(void* const* d_in, const int* in_sizes, int n_in,
                              void* d_out, int out_size, void* d_ws, size_t ws_size,
                              hipStream_t stream) {
  const float* feat = (const float*)d_in[0];
  const int* nbr    = (const int*)d_in[1];
  const void* mask  = d_in[2];
  const float* w1   = (const float*)d_in[3];
  const float* b1   = (const float*)d_in[4];
  const float* w2   = (const float*)d_in[5];
  const float* b2   = (const float*)d_in[6];

  char* ws = (char*)d_ws;
  unsigned short* featb = (unsigned short*)ws;                    // 33,554,432 B
  unsigned short* hb    = (unsigned short*)(ws + 33554432);       // 33,554,432 B
  unsigned char*  maskb = (unsigned char*)(ws + 67108864);        //  7,077,888 B
  unsigned short* wf1   = (unsigned short*)(ws + 74186752);       //    221,184 B
  unsigned short* wf2   = (unsigned short*)(ws + 74407936);       //    221,184 B
  int*            flag  = (int*)(ws + 74629120);

  prep_flag_k<<<1, 64, 0, stream>>>((const unsigned*)mask, flag);
  prep_mask_k<<<4096, 256, 0, stream>>>(mask, flag, maskb, KOFF * N_VOX);
  prep_feat_k<<<8192, 256, 0, stream>>>(feat, featb, N_VOX * CCH / 8);
  prep_w_k<<<432, 256, 0, stream>>>(w1, wf1);
  prep_w_k<<<432, 256, 0, stream>>>(w2, wf2);

  conv_layer_k<1><<<2048, 256, 0, stream>>>((const v8s*)featb, nbr, maskb,
                                            (const v8s*)wf1, b1, nullptr, (void*)hb);
  conv_layer_k<2><<<2048, 256, 0, stream>>>((const v8s*)hb, nbr, maskb,
                                            (const v8s*)wf2, b2, feat, (void*)d_out);
}

// Round 6
// 273.701 us; speedup vs baseline: 2.0509x; 1.0541x over previous
//
#include <hip/hip_runtime.h>
#include <stdint.h>

#define N_VOX 262144
#define CCH 64
#define KOFF 27

typedef short v8s __attribute__((ext_vector_type(8)));
typedef float v4f __attribute__((ext_vector_type(4)));

__device__ __forceinline__ unsigned short f2bf(float f) {
  unsigned u = __float_as_uint(f);
  u += 0x7fff + ((u >> 16) & 1);   // RNE
  return (unsigned short)(u >> 16);
}

// --- deterministic sniff of the mask buffer's dtype (byte-bool vs 32-bit) ---
__global__ void prep_flag_k(const unsigned* __restrict__ m, int* __restrict__ flag) {
  if (threadIdx.x == 0) {
    int wordlike = 1;  // int32 0/1 or float32 0.0/1.0
    for (int i = 0; i < 256; ++i) {
      unsigned v = m[i];
      if (v > 1u && v != 0x3f800000u) { wordlike = 0; break; }
    }
    *flag = wordlike ? 0 : 2;   // 0: read as u32 words, 2: read as bytes
  }
}

__global__ void prep_mask_k(const void* __restrict__ m, const int* __restrict__ flag,
                            unsigned char* __restrict__ mb, int n) {
  int f = *flag;
  for (int i = blockIdx.x * blockDim.x + threadIdx.x; i < n; i += gridDim.x * blockDim.x) {
    unsigned char v;
    if (f == 2) v = (((const unsigned char*)m)[i] != 0);
    else        v = (((const unsigned*)m)[i] != 0u);
    mb[i] = v;
  }
}

// --- features fp32 -> bf16 table (halves gather traffic, frags load direct) ---
__global__ void prep_feat_k(const float* __restrict__ src, unsigned short* __restrict__ dst, int n8) {
  int i = blockIdx.x * blockDim.x + threadIdx.x;
  if (i >= n8) return;
  const float4* s4 = (const float4*)src;
  float4 a = s4[i * 2], b = s4[i * 2 + 1];
  v8s v;
  v[0] = (short)f2bf(a.x); v[1] = (short)f2bf(a.y);
  v[2] = (short)f2bf(a.z); v[3] = (short)f2bf(a.w);
  v[4] = (short)f2bf(b.x); v[5] = (short)f2bf(b.y);
  v[6] = (short)f2bf(b.z); v[7] = (short)f2bf(b.w);
  ((v8s*)dst)[i] = v;
}

// --- W [27][cin][cout] fp32 -> frag-order bf16: wf[k][ct*2+half][lane][8]
// so each wave's B-fragment load is one fully-coalesced dwordx4 per lane. ---
__global__ void prep_w_k(const float* __restrict__ w, unsigned short* __restrict__ wt) {
  int i = blockIdx.x * blockDim.x + threadIdx.x;
  if (i >= KOFF * CCH * CCH) return;          // 110592
  int e = i & 7, lane = (i >> 3) & 63, ch = (i >> 9) & 7, k = i >> 12;
  int ct = ch >> 1, half = ch & 1;
  int col = ct * 16 + (lane & 15);
  int kk = half * 32 + ((lane >> 4) << 3) + e;
  wt[i] = f2bf(w[(k << 12) + (kk << 6) + col]);
}

// One pipeline stage. Consumes A(k) [gathered 2 stages ago, register-resident
// so the compiler's scoreboard emits exact vmcnt waits] and W(k) [prefetched 1
// stage ago]. Then refills the just-consumed registers: W(k+1)->bu, gather
// A(k+2) into a* (idx/mask preloaded 2 stages ago), idx/mask(k+4) into j/n.
// No copies, no barriers, no manual waitcnt.
__device__ __forceinline__ void conv_body(
    int k, bool last,
    const v8s* __restrict__ src, const int* __restrict__ nbr,
    const unsigned char* __restrict__ mb, const v8s* __restrict__ wf,
    int r0, int r1, int g, int lane,
    v8s& a0, v8s& a1, v8s& a2, v8s& a3,
    v8s (&bu)[8], int& j0, int& j1, bool& n0, bool& n1,
    v4f (&acc0)[4], v4f (&acc1)[4])
{
#pragma unroll
  for (int ct = 0; ct < 4; ++ct) {
    acc0[ct] = __builtin_amdgcn_mfma_f32_16x16x32_bf16(a0, bu[ct],     acc0[ct], 0, 0, 0);
    acc0[ct] = __builtin_amdgcn_mfma_f32_16x16x32_bf16(a1, bu[4 + ct], acc0[ct], 0, 0, 0);
    acc1[ct] = __builtin_amdgcn_mfma_f32_16x16x32_bf16(a2, bu[ct],     acc1[ct], 0, 0, 0);
    acc1[ct] = __builtin_amdgcn_mfma_f32_16x16x32_bf16(a3, bu[4 + ct], acc1[ct], 0, 0, 0);
  }
  if (last) return;

  // W(k+1) -> bu (frag-order: one coalesced dwordx4 per lane per fragment)
#pragma unroll
  for (int ct = 0; ct < 4; ++ct) {
    bu[ct]     = wf[((k + 1) * 8 + ct * 2) * 64 + lane];
    bu[4 + ct] = wf[((k + 1) * 8 + ct * 2 + 1) * 64 + lane];
  }

  // gathers for k+2 (j/n hold idx/mask(k+2), loaded 2 stages ago)
  if (k + 2 < KOFF) {
    a0 = {}; a1 = {}; a2 = {}; a3 = {};
    if (n0) { a0 = src[j0 * 8 + g]; a1 = src[j0 * 8 + 4 + g]; }
    if (n1) { a2 = src[j1 * 8 + g]; a3 = src[j1 * 8 + 4 + g]; }
  }

  // idx/mask for k+4 (into the slots just consumed)
  const int kj = (k + 4 < KOFF) ? k + 4 : KOFF - 1;
  j0 = nbr[kj * N_VOX + r0]; j1 = nbr[kj * N_VOX + r1];
  n0 = mb[kj * N_VOX + r0];  n1 = mb[kj * N_VOX + r1];
}

// --- one sparse-conv layer: barrier-free, copy-free 2-stage pipeline ---
// 128 rows/block (4 waves x 32 rows). LAYER==1: bf16 h. LAYER==2: f32+resid.
// launch_bounds (256,3): 170-reg cap -> no spill (R4's (256,4)=128 spilled).
template <int LAYER>
__global__ __launch_bounds__(256, 3)
void conv_layer_k(const v8s* __restrict__ src, const int* __restrict__ nbr,
                  const unsigned char* __restrict__ mb,
                  const v8s* __restrict__ wf, const float* __restrict__ bias,
                  const float* __restrict__ resid, void* __restrict__ outp) {
  const int tid = threadIdx.x;
  const int lane = tid & 63;
  const int wv = tid >> 6;
  const int l15 = lane & 15;
  const int g = lane >> 4;
  const int rowbase = blockIdx.x * 128 + wv * 32;
  const int r0 = rowbase + l15;
  const int r1 = rowbase + 16 + l15;

  // ---- prologue: A(0)->aE, A(1)->aO, idx/mask(2)->E, (3)->O, W(0)->bu ----
  int jE0 = nbr[r0], jE1 = nbr[r1];
  int jO0 = nbr[N_VOX + r0], jO1 = nbr[N_VOX + r1];
  bool nE0 = mb[r0], nE1 = mb[r1];
  bool nO0 = mb[N_VOX + r0], nO1 = mb[N_VOX + r1];

  v8s aE0 = {}, aE1 = {}, aE2 = {}, aE3 = {};
  v8s aO0 = {}, aO1 = {}, aO2 = {}, aO3 = {};
  if (nE0) { aE0 = src[jE0 * 8 + g]; aE1 = src[jE0 * 8 + 4 + g]; }
  if (nE1) { aE2 = src[jE1 * 8 + g]; aE3 = src[jE1 * 8 + 4 + g]; }
  if (nO0) { aO0 = src[jO0 * 8 + g]; aO1 = src[jO0 * 8 + 4 + g]; }
  if (nO1) { aO2 = src[jO1 * 8 + g]; aO3 = src[jO1 * 8 + 4 + g]; }

  jE0 = nbr[2 * N_VOX + r0]; jE1 = nbr[2 * N_VOX + r1];
  nE0 = mb[2 * N_VOX + r0];  nE1 = mb[2 * N_VOX + r1];
  jO0 = nbr[3 * N_VOX + r0]; jO1 = nbr[3 * N_VOX + r1];
  nO0 = mb[3 * N_VOX + r0];  nO1 = mb[3 * N_VOX + r1];

  v8s bu[8];
#pragma unroll
  for (int ct = 0; ct < 4; ++ct) {
    bu[ct]     = wf[(ct * 2) * 64 + lane];
    bu[4 + ct] = wf[(ct * 2 + 1) * 64 + lane];
  }

  v4f acc0[4] = {}, acc1[4] = {};

#pragma unroll 1
  for (int k = 0; k < KOFF - 1; k += 2) {
    conv_body(k,     false, src, nbr, mb, wf, r0, r1, g, lane,
              aE0, aE1, aE2, aE3, bu, jE0, jE1, nE0, nE1, acc0, acc1);
    conv_body(k + 1, false, src, nbr, mb, wf, r0, r1, g, lane,
              aO0, aO1, aO2, aO3, bu, jO0, jO1, nO0, nO1, acc0, acc1);
  }
  conv_body(KOFF - 1, true, src, nbr, mb, wf, r0, r1, g, lane,
            aE0, aE1, aE2, aE3, bu, jE0, jE1, nE0, nE1, acc0, acc1);

  float bv[4];
#pragma unroll
  for (int ct = 0; ct < 4; ++ct) bv[ct] = bias[ct * 16 + l15];

#pragma unroll
  for (int rt = 0; rt < 2; ++rt) {
    int row0 = rowbase + rt * 16 + g * 4;   // D row = (lane>>4)*4 + i
#pragma unroll
    for (int ct = 0; ct < 4; ++ct) {
      int col = ct * 16 + l15;              // D col = lane & 15
      const v4f& a = rt ? acc1[ct] : acc0[ct];
#pragma unroll
      for (int i = 0; i < 4; ++i) {
        float v = a[i] + bv[ct];
        int o = (row0 + i) * CCH + col;
        if (LAYER == 1) ((unsigned short*)outp)[o] = f2bf(v);
        else            ((float*)outp)[o] = v + resid[o];
      }
    }
  }
}

extern "C" void kernel_launch(void* const* d_in, const int* in_sizes, int n_in,
                              void* d_out, int out_size, void* d_ws, size_t ws_size,
                              hipStream_t stream) {
  const float* feat = (const float*)d_in[0];
  const int* nbr    = (const int*)d_in[1];
  const void* mask  = d_in[2];
  const float* w1   = (const float*)d_in[3];
  const float* b1   = (const float*)d_in[4];
  const float* w2   = (const float*)d_in[5];
  const float* b2   = (const float*)d_in[6];

  char* ws = (char*)d_ws;
  unsigned short* featb = (unsigned short*)ws;                    // 33,554,432 B
  unsigned short* hb    = (unsigned short*)(ws + 33554432);       // 33,554,432 B
  unsigned char*  maskb = (unsigned char*)(ws + 67108864);        //  7,077,888 B
  unsigned short* wf1   = (unsigned short*)(ws + 74186752);       //    221,184 B
  unsigned short* wf2   = (unsigned short*)(ws + 74407936);       //    221,184 B
  int*            flag  = (int*)(ws + 74629120);

  prep_flag_k<<<1, 64, 0, stream>>>((const unsigned*)mask, flag);
  prep_mask_k<<<4096, 256, 0, stream>>>(mask, flag, maskb, KOFF * N_VOX);
  prep_feat_k<<<8192, 256, 0, stream>>>(feat, featb, N_VOX * CCH / 8);
  prep_w_k<<<432, 256, 0, stream>>>(w1, wf1);
  prep_w_k<<<432, 256, 0, stream>>>(w2, wf2);

  conv_layer_k<1><<<2048, 256, 0, stream>>>((const v8s*)featb, nbr, maskb,
                                            (const v8s*)wf1, b1, nullptr, (void*)hb);
  conv_layer_k<2><<<2048, 256, 0, stream>>>((const v8s*)hb, nbr, maskb,
                                            (const v8s*)wf2, b2, feat, (void*)d_out);
}

// Round 7
// 259.952 us; speedup vs baseline: 2.1594x; 1.0529x over previous
//
#include <hip/hip_runtime.h>
#include <stdint.h>

#define N_VOX 262144
#define CCH 64
#define KOFF 27

typedef short v8s __attribute__((ext_vector_type(8)));
typedef float v4f __attribute__((ext_vector_type(4)));

__device__ __forceinline__ unsigned short f2bf(float f) {
  unsigned u = __float_as_uint(f);
  u += 0x7fff + ((u >> 16) & 1);   // RNE
  return (unsigned short)(u >> 16);
}

// --- deterministic sniff of the mask buffer's dtype (byte-bool vs 32-bit) ---
__global__ void prep_flag_k(const unsigned* __restrict__ m, int* __restrict__ flag) {
  if (threadIdx.x == 0) {
    int wordlike = 1;  // int32 0/1 or float32 0.0/1.0
    for (int i = 0; i < 256; ++i) {
      unsigned v = m[i];
      if (v > 1u && v != 0x3f800000u) { wordlike = 0; break; }
    }
    *flag = wordlike ? 0 : 2;   // 0: read as u32 words, 2: read as bytes
  }
}

__global__ void prep_mask_k(const void* __restrict__ m, const int* __restrict__ flag,
                            unsigned char* __restrict__ mb, int n) {
  int f = *flag;
  for (int i = blockIdx.x * blockDim.x + threadIdx.x; i < n; i += gridDim.x * blockDim.x) {
    unsigned char v;
    if (f == 2) v = (((const unsigned char*)m)[i] != 0);
    else        v = (((const unsigned*)m)[i] != 0u);
    mb[i] = v;
  }
}

// --- features fp32 -> bf16 table ---
__global__ void prep_feat_k(const float* __restrict__ src, unsigned short* __restrict__ dst, int n8) {
  int i = blockIdx.x * blockDim.x + threadIdx.x;
  if (i >= n8) return;
  const float4* s4 = (const float4*)src;
  float4 a = s4[i * 2], b = s4[i * 2 + 1];
  v8s v;
  v[0] = (short)f2bf(a.x); v[1] = (short)f2bf(a.y);
  v[2] = (short)f2bf(a.z); v[3] = (short)f2bf(a.w);
  v[4] = (short)f2bf(b.x); v[5] = (short)f2bf(b.y);
  v[6] = (short)f2bf(b.z); v[7] = (short)f2bf(b.w);
  ((v8s*)dst)[i] = v;
}

// --- W [27][cin][cout] fp32 -> frag-order bf16: wf[k][ch][lane][8] so both the
// LDS staging copy and the per-lane B-fragment reads are fully linear. ---
__global__ void prep_w_k(const float* __restrict__ w, unsigned short* __restrict__ wt) {
  int i = blockIdx.x * blockDim.x + threadIdx.x;
  if (i >= KOFF * CCH * CCH) return;          // 110592
  int e = i & 7, lane = (i >> 3) & 63, ch = (i >> 9) & 7, k = i >> 12;
  int ct = ch >> 1, half = ch & 1;
  int col = ct * 16 + (lane & 15);
  int kk = half * 32 + ((lane >> 4) << 3) + e;
  wt[i] = f2bf(w[(k << 12) + (kk << 6) + col]);
}

// barrier that keeps VMEM (gathers, W prefetch) in flight; drains only LDS
__device__ __forceinline__ void barrier_keep_vmem() {
  asm volatile("s_waitcnt lgkmcnt(0)" ::: "memory");
  __builtin_amdgcn_s_barrier();
  __builtin_amdgcn_sched_barrier(0);
}

// One body, k-th offset. g0..g3: full-row gathers (row = i*8 + (lane>>3),
// chunk = lane&7) issued 2 bodies ago. idxv/mnxt hold idx/mask(k+2) vectors
// (lane&31 = row); mcur holds mask(k). W(k) is in ldsW[k&1].
__device__ __forceinline__ void conv_body(
    int k, bool last, char* Wc, char* Wn, char* myA,
    const v8s* __restrict__ src8, const int* __restrict__ nbr,
    const unsigned char* __restrict__ mb, const v8s* __restrict__ wfg,
    int tid, int lane, int rowbase,
    v8s& g0, v8s& g1, v8s& g2, v8s& g3,
    int& idxv, int& mcur, int& mnxt,
    v4f (&acc0)[4], v4f (&acc1)[4])
{
  const int l7 = lane & 7;
  const int l15 = lane & 15;
  const int hi = lane >> 4;   // 0..3
  const int r8 = lane >> 3;   // 0..7

  // 1. W(k+1) global prefetch (2 fully-coalesced dwordx4; ds_write at body end)
  v8s w0 = {}, w1 = {};
  if (!last) {
    w0 = wfg[(k + 1) * 512 + tid];
    w1 = wfg[(k + 1) * 512 + 256 + tid];
  }

  // 2. B-fragments from the LDS W copy (8 x contiguous ds_read_b128)
  v8s bu0 = *(const v8s*)(Wc + 0 * 1024 + lane * 16);
  v8s bu1 = *(const v8s*)(Wc + 1 * 1024 + lane * 16);
  v8s bu2 = *(const v8s*)(Wc + 2 * 1024 + lane * 16);
  v8s bu3 = *(const v8s*)(Wc + 3 * 1024 + lane * 16);
  v8s bu4 = *(const v8s*)(Wc + 4 * 1024 + lane * 16);
  v8s bu5 = *(const v8s*)(Wc + 5 * 1024 + lane * 16);
  v8s bu6 = *(const v8s*)(Wc + 6 * 1024 + lane * 16);
  v8s bu7 = *(const v8s*)(Wc + 7 * 1024 + lane * 16);

  // 3. transpose A(k): write gathered rows (swizzled: chunk ^ (row&7))
  {
    int woff = r8 * 128 + ((l7 ^ r8) * 16);
    *(v8s*)(myA + woff)        = g0;
    *(v8s*)(myA + 1024 + woff) = g1;
    *(v8s*)(myA + 2048 + woff) = g2;
    *(v8s*)(myA + 3072 + woff) = g3;
  }
  // 4. read A-fragments (swizzle-matched; row = l15, chunk = hi / hi+4)
  const int rb = l15 * 128;
  const int x0 = ((hi ^ l7) * 16);
  const int x1 = (((hi + 4) ^ l7) * 16);
  v8s a0 = *(const v8s*)(myA + rb + x0);
  v8s a1 = *(const v8s*)(myA + rb + x1);
  v8s a2 = *(const v8s*)(myA + 2048 + rb + x0);
  v8s a3 = *(const v8s*)(myA + 2048 + rb + x1);

  // 5. zero masked rows (mask(k) redistributed to frag lanes)
  int mlo = __shfl(mcur, l15, 64);
  int mhi = __shfl(mcur, 16 + l15, 64);
  if (!mlo) { a0 = (v8s){}; a1 = (v8s){}; }
  if (!mhi) { a2 = (v8s){}; a3 = (v8s){}; }

  // 6. MFMA
#pragma unroll
  for (int ct = 0; ct < 4; ++ct) {
    const v8s& blo = ct == 0 ? bu0 : ct == 1 ? bu2 : ct == 2 ? bu4 : bu6;
    const v8s& bhi = ct == 0 ? bu1 : ct == 1 ? bu3 : ct == 2 ? bu5 : bu7;
    acc0[ct] = __builtin_amdgcn_mfma_f32_16x16x32_bf16(a0, blo, acc0[ct], 0, 0, 0);
    acc0[ct] = __builtin_amdgcn_mfma_f32_16x16x32_bf16(a1, bhi, acc0[ct], 0, 0, 0);
    acc1[ct] = __builtin_amdgcn_mfma_f32_16x16x32_bf16(a2, blo, acc1[ct], 0, 0, 0);
    acc1[ct] = __builtin_amdgcn_mfma_f32_16x16x32_bf16(a3, bhi, acc1[ct], 0, 0, 0);
  }
  if (last) return;

  // 7. full-row gathers for k+2 (1 line-touch per active row; ~60% skipped)
  if (k + 2 < KOFF) {
    int ri0 = __shfl(idxv, r8, 64),      rm0 = __shfl(mnxt, r8, 64);
    int ri1 = __shfl(idxv, 8 + r8, 64),  rm1 = __shfl(mnxt, 8 + r8, 64);
    int ri2 = __shfl(idxv, 16 + r8, 64), rm2 = __shfl(mnxt, 16 + r8, 64);
    int ri3 = __shfl(idxv, 24 + r8, 64), rm3 = __shfl(mnxt, 24 + r8, 64);
    g0 = (v8s){}; g1 = (v8s){}; g2 = (v8s){}; g3 = (v8s){};
    if (rm0) g0 = src8[(size_t)ri0 * 8 + l7];
    if (rm1) g1 = src8[(size_t)ri1 * 8 + l7];
    if (rm2) g2 = src8[(size_t)ri2 * 8 + l7];
    if (rm3) g3 = src8[(size_t)ri3 * 8 + l7];
    mcur = mnxt;
    int kj = (k + 4 < KOFF) ? k + 4 : KOFF - 1;
    idxv = nbr[kj * N_VOX + rowbase + (lane & 31)];
    mnxt = mb[kj * N_VOX + rowbase + (lane & 31)];
  }

  // 8. stage W(k+1) into the other LDS buffer; lgkm-only barrier
  *(v8s*)(Wn + tid * 16)         = w0;
  *(v8s*)(Wn + (256 + tid) * 16) = w1;
  barrier_keep_vmem();
}

// --- one sparse-conv layer ---
// 4 waves x 32 rows; W double-buffered in LDS; per-wave 4KB transpose buffer.
template <int LAYER>
__global__ __launch_bounds__(256, 3)
void conv_layer_k(const v8s* __restrict__ src8, const int* __restrict__ nbr,
                  const unsigned char* __restrict__ mb,
                  const v8s* __restrict__ wfg, const float* __restrict__ bias,
                  const float* __restrict__ resid, void* __restrict__ outp) {
  __shared__ char ldsW[2][8192];
  __shared__ char ldsA[4][4096];
  const int tid = threadIdx.x;
  const int lane = tid & 63;
  const int wv = tid >> 6;
  const int l7 = lane & 7;
  const int l15 = lane & 15;
  const int g = lane >> 4;
  const int r8 = lane >> 3;
  const int rowbase = blockIdx.x * 128 + wv * 32;
  char* myA = ldsA[wv];

  // ---- prologue ----
  int iv0 = nbr[rowbase + (lane & 31)];
  int mv0 = mb[rowbase + (lane & 31)];
  int iv1 = nbr[N_VOX + rowbase + (lane & 31)];
  int mv1 = mb[N_VOX + rowbase + (lane & 31)];

  v8s gE0 = {}, gE1 = {}, gE2 = {}, gE3 = {};
  v8s gO0 = {}, gO1 = {}, gO2 = {}, gO3 = {};
  {
    int ri, rm;
    ri = __shfl(iv0, r8, 64);      rm = __shfl(mv0, r8, 64);      if (rm) gE0 = src8[(size_t)ri * 8 + l7];
    ri = __shfl(iv0, 8 + r8, 64);  rm = __shfl(mv0, 8 + r8, 64);  if (rm) gE1 = src8[(size_t)ri * 8 + l7];
    ri = __shfl(iv0, 16 + r8, 64); rm = __shfl(mv0, 16 + r8, 64); if (rm) gE2 = src8[(size_t)ri * 8 + l7];
    ri = __shfl(iv0, 24 + r8, 64); rm = __shfl(mv0, 24 + r8, 64); if (rm) gE3 = src8[(size_t)ri * 8 + l7];
    ri = __shfl(iv1, r8, 64);      rm = __shfl(mv1, r8, 64);      if (rm) gO0 = src8[(size_t)ri * 8 + l7];
    ri = __shfl(iv1, 8 + r8, 64);  rm = __shfl(mv1, 8 + r8, 64);  if (rm) gO1 = src8[(size_t)ri * 8 + l7];
    ri = __shfl(iv1, 16 + r8, 64); rm = __shfl(mv1, 16 + r8, 64); if (rm) gO2 = src8[(size_t)ri * 8 + l7];
    ri = __shfl(iv1, 24 + r8, 64); rm = __shfl(mv1, 24 + r8, 64); if (rm) gO3 = src8[(size_t)ri * 8 + l7];
  }

  int idxE = nbr[2 * N_VOX + rowbase + (lane & 31)];
  int mnxtE = mb[2 * N_VOX + rowbase + (lane & 31)];
  int idxO = nbr[3 * N_VOX + rowbase + (lane & 31)];
  int mnxtO = mb[3 * N_VOX + rowbase + (lane & 31)];
  int mcurE = mv0, mcurO = mv1;

  // stage W(0)
  {
    v8s w0 = wfg[tid], w1 = wfg[256 + tid];
    *(v8s*)(ldsW[0] + tid * 16) = w0;
    *(v8s*)(ldsW[0] + (256 + tid) * 16) = w1;
  }
  barrier_keep_vmem();

  v4f acc0[4] = {}, acc1[4] = {};

#pragma unroll 1
  for (int k = 0; k < KOFF - 1; k += 2) {
    conv_body(k,     false, ldsW[0], ldsW[1], myA, src8, nbr, mb, wfg,
              tid, lane, rowbase, gE0, gE1, gE2, gE3, idxE, mcurE, mnxtE, acc0, acc1);
    conv_body(k + 1, false, ldsW[1], ldsW[0], myA, src8, nbr, mb, wfg,
              tid, lane, rowbase, gO0, gO1, gO2, gO3, idxO, mcurO, mnxtO, acc0, acc1);
  }
  conv_body(KOFF - 1, true, ldsW[0], ldsW[1], myA, src8, nbr, mb, wfg,
            tid, lane, rowbase, gE0, gE1, gE2, gE3, idxE, mcurE, mnxtE, acc0, acc1);

  float bv[4];
#pragma unroll
  for (int ct = 0; ct < 4; ++ct) bv[ct] = bias[ct * 16 + l15];

#pragma unroll
  for (int rt = 0; rt < 2; ++rt) {
    int row0 = rowbase + rt * 16 + g * 4;   // D row = (lane>>4)*4 + i
#pragma unroll
    for (int ct = 0; ct < 4; ++ct) {
      int col = ct * 16 + l15;              // D col = lane & 15
      const v4f& a = rt ? acc1[ct] : acc0[ct];
#pragma unroll
      for (int i = 0; i < 4; ++i) {
        float v = a[i] + bv[ct];
        int o = (row0 + i) * CCH + col;
        if (LAYER == 1) ((unsigned short*)outp)[o] = f2bf(v);
        else            ((float*)outp)[o] = v + resid[o];
      }
    }
  }
}

extern "C" void kernel_launch(void* const* d_in, const int* in_sizes, int n_in,
                              void* d_out, int out_size, void* d_ws, size_t ws_size,
                              hipStream_t stream) {
  const float* feat = (const float*)d_in[0];
  const int* nbr    = (const int*)d_in[1];
  const void* mask  = d_in[2];
  const float* w1   = (const float*)d_in[3];
  const float* b1   = (const float*)d_in[4];
  const float* w2   = (const float*)d_in[5];
  const float* b2   = (const float*)d_in[6];

  char* ws = (char*)d_ws;
  unsigned short* featb = (unsigned short*)ws;                    // 33,554,432 B
  unsigned short* hb    = (unsigned short*)(ws + 33554432);       // 33,554,432 B
  unsigned char*  maskb = (unsigned char*)(ws + 67108864);        //  7,077,888 B
  unsigned short* wf1   = (unsigned short*)(ws + 74186752);       //    221,184 B
  unsigned short* wf2   = (unsigned short*)(ws + 74407936);       //    221,184 B
  int*            flag  = (int*)(ws + 74629120);

  prep_flag_k<<<1, 64, 0, stream>>>((const unsigned*)mask, flag);
  prep_mask_k<<<4096, 256, 0, stream>>>(mask, flag, maskb, KOFF * N_VOX);
  prep_feat_k<<<8192, 256, 0, stream>>>(feat, featb, N_VOX * CCH / 8);
  prep_w_k<<<432, 256, 0, stream>>>(w1, wf1);
  prep_w_k<<<432, 256, 0, stream>>>(w2, wf2);

  conv_layer_k<1><<<2048, 256, 0, stream>>>((const v8s*)featb, nbr, maskb,
                                            (const v8s*)wf1, b1, nullptr, (void*)hb);
  conv_layer_k<2><<<2048, 256, 0, stream>>>((const v8s*)hb, nbr, maskb,
                                            (const v8s*)wf2, b2, feat, (void*)d_out);
}